// Round 1
// baseline (442.788 us; speedup 1.0000x reference)
//
#include <hip/hip_runtime.h>

// x:   [N=256, 3, 3, num=256, F=128] fp32, C-order
// out: [N=256, 3, 3, G=128,  F=128] fp32
// Per (n,g,f): keep matrix 2g or 2g+1 with larger acos(clip((tr-1)/2,-1,1)).
// acos strictly decreasing => pick candidate 1 iff clip(c1) < clip(c0);
// ties -> candidate 0 (argmax first-max semantics).
//
// R2 probe: loads are now PLAIN (cache-allocating) instead of nontemporal.
// Input is 288 MiB, re-read every timed iteration; allowing L2/L3 allocation
// lets the 256 MiB Infinity Cache serve most re-reads. Stores remain
// nontemporal: output is never re-read, and NT stores avoid evicting the
// input's L3 lines. Single-variable change vs. the 415.4 us baseline.

typedef float vf4 __attribute__((ext_vector_type(4)));  // native clang vector:
// required because __builtin_nontemporal_store rejects HIP_vector_type.

__global__ __launch_bounds__(256) void pool_space_kernel(
    const vf4* __restrict__ x, vf4* __restrict__ out)
{
    constexpr int FV    = 32;              // F/4
    constexpr int G     = 128;
    constexpr int IN_E  = 256 * FV;        // 8192 vf4 per (i,j) plane
    constexpr int IN_N  = 9 * IN_E;
    constexpr int OUT_E = G * FV;          // 4096
    constexpr int OUT_N = 9 * OUT_E;

    const int tid = blockIdx.x * blockDim.x + threadIdx.x;
    const int fv  = tid & (FV - 1);
    const int g   = (tid >> 5) & (G - 1);
    const int n   = tid >> 12;

    const int inBase  = n * IN_N + (2 * g) * FV + fv;
    const int outBase = n * OUT_N + g * FV + fv;

    // Issue all 18 loads up front (max MLP). Diagonals first (they gate the pick).
    vf4 d0a = x[inBase + 0 * IN_E];
    vf4 d0b = x[inBase + 0 * IN_E + FV];
    vf4 d4a = x[inBase + 4 * IN_E];
    vf4 d4b = x[inBase + 4 * IN_E + FV];
    vf4 d8a = x[inBase + 8 * IN_E];
    vf4 d8b = x[inBase + 8 * IN_E + FV];

    vf4 oa[6], ob[6];
    constexpr int OD[6] = {1, 2, 3, 5, 6, 7};
#pragma unroll
    for (int i = 0; i < 6; ++i) {
        oa[i] = x[inBase + OD[i] * IN_E];
        ob[i] = x[inBase + OD[i] * IN_E + FV];
    }

    // Per-component pick: pk[k] true -> take candidate 1.
    bool pk[4];
#pragma unroll
    for (int k = 0; k < 4; ++k) {
        const float tr0 = d0a[k] + d4a[k] + d8a[k];
        const float tr1 = d0b[k] + d4b[k] + d8b[k];
        const float c0 = fminf(fmaxf((tr0 - 1.0f) * 0.5f, -1.0f), 1.0f);
        const float c1 = fminf(fmaxf((tr1 - 1.0f) * 0.5f, -1.0f), 1.0f);
        pk[k] = (c1 < c0);
    }

    auto sel = [&](vf4 a, vf4 b) {
        vf4 r;
        r[0] = pk[0] ? b[0] : a[0];
        r[1] = pk[1] ? b[1] : a[1];
        r[2] = pk[2] ? b[2] : a[2];
        r[3] = pk[3] ? b[3] : a[3];
        return r;
    };

    // Diagonal outputs reuse the already-loaded registers (no reload).
    __builtin_nontemporal_store(sel(d0a, d0b), &out[outBase + 0 * OUT_E]);
    __builtin_nontemporal_store(sel(d4a, d4b), &out[outBase + 4 * OUT_E]);
    __builtin_nontemporal_store(sel(d8a, d8b), &out[outBase + 8 * OUT_E]);
#pragma unroll
    for (int i = 0; i < 6; ++i) {
        __builtin_nontemporal_store(sel(oa[i], ob[i]), &out[outBase + OD[i] * OUT_E]);
    }
}

extern "C" void kernel_launch(void* const* d_in, const int* in_sizes, int n_in,
                              void* d_out, int out_size, void* d_ws, size_t ws_size,
                              hipStream_t stream) {
    const vf4* x = reinterpret_cast<const vf4*>(d_in[0]);
    vf4* out = reinterpret_cast<vf4*>(d_out);

    // total threads = N * G * F/4 = 256 * 128 * 32 = 1,048,576
    const int threads = 256;
    const int blocks = (256 * 128 * 32) / threads;  // 4096
    pool_space_kernel<<<blocks, threads, 0, stream>>>(x, out);
}

// Round 2
// 421.375 us; speedup vs baseline: 1.0508x; 1.0508x over previous
//
#include <hip/hip_runtime.h>

// x:   [N=256, 3, 3, num=256, F=128] fp32, C-order
// out: [N=256, 3, 3, G=128,  F=128] fp32
// Per (n,g,f): keep matrix 2g or 2g+1 with larger acos(clip((tr-1)/2,-1,1)).
// acos strictly decreasing => pick candidate 1 iff clip(c1) < clip(c0);
// ties -> candidate 0 (argmax first-max semantics).
//
// R2 result: plain loads cost +27 us vs NT loads (re-poison fill flushes L3,
// so allocating a 302 MB single-use read stream only thrashes). NT loads
// restored here.
// R3 probe: stores PLAIN (was NT). The 1.2 GB poison fill just touched the
// output lines; if they are L3-resident, allocating stores write-hit L3 and
// defer the 151 MB HBM writeback out of the kernel's critical window.
// Single-variable change vs the 415.4 us R0 kernel.

typedef float vf4 __attribute__((ext_vector_type(4)));  // native clang vector:
// required because __builtin_nontemporal_load rejects HIP_vector_type.

__global__ __launch_bounds__(256) void pool_space_kernel(
    const vf4* __restrict__ x, vf4* __restrict__ out)
{
    constexpr int FV    = 32;              // F/4
    constexpr int G     = 128;
    constexpr int IN_E  = 256 * FV;        // 8192 vf4 per (i,j) plane
    constexpr int IN_N  = 9 * IN_E;
    constexpr int OUT_E = G * FV;          // 4096
    constexpr int OUT_N = 9 * OUT_E;

    const int tid = blockIdx.x * blockDim.x + threadIdx.x;
    const int fv  = tid & (FV - 1);
    const int g   = (tid >> 5) & (G - 1);
    const int n   = tid >> 12;

    const int inBase  = n * IN_N + (2 * g) * FV + fv;
    const int outBase = n * OUT_N + g * FV + fv;

    // Issue all 18 loads up front (max MLP). Diagonals first (they gate the pick).
    vf4 d0a = __builtin_nontemporal_load(&x[inBase + 0 * IN_E]);
    vf4 d0b = __builtin_nontemporal_load(&x[inBase + 0 * IN_E + FV]);
    vf4 d4a = __builtin_nontemporal_load(&x[inBase + 4 * IN_E]);
    vf4 d4b = __builtin_nontemporal_load(&x[inBase + 4 * IN_E + FV]);
    vf4 d8a = __builtin_nontemporal_load(&x[inBase + 8 * IN_E]);
    vf4 d8b = __builtin_nontemporal_load(&x[inBase + 8 * IN_E + FV]);

    vf4 oa[6], ob[6];
    constexpr int OD[6] = {1, 2, 3, 5, 6, 7};
#pragma unroll
    for (int i = 0; i < 6; ++i) {
        oa[i] = __builtin_nontemporal_load(&x[inBase + OD[i] * IN_E]);
        ob[i] = __builtin_nontemporal_load(&x[inBase + OD[i] * IN_E + FV]);
    }

    // Per-component pick: pk[k] true -> take candidate 1.
    bool pk[4];
#pragma unroll
    for (int k = 0; k < 4; ++k) {
        const float tr0 = d0a[k] + d4a[k] + d8a[k];
        const float tr1 = d0b[k] + d4b[k] + d8b[k];
        const float c0 = fminf(fmaxf((tr0 - 1.0f) * 0.5f, -1.0f), 1.0f);
        const float c1 = fminf(fmaxf((tr1 - 1.0f) * 0.5f, -1.0f), 1.0f);
        pk[k] = (c1 < c0);
    }

    auto sel = [&](vf4 a, vf4 b) {
        vf4 r;
        r[0] = pk[0] ? b[0] : a[0];
        r[1] = pk[1] ? b[1] : a[1];
        r[2] = pk[2] ? b[2] : a[2];
        r[3] = pk[3] ? b[3] : a[3];
        return r;
    };

    // Diagonal outputs reuse the already-loaded registers (no reload).
    out[outBase + 0 * OUT_E] = sel(d0a, d0b);
    out[outBase + 4 * OUT_E] = sel(d4a, d4b);
    out[outBase + 8 * OUT_E] = sel(d8a, d8b);
#pragma unroll
    for (int i = 0; i < 6; ++i) {
        out[outBase + OD[i] * OUT_E] = sel(oa[i], ob[i]);
    }
}

extern "C" void kernel_launch(void* const* d_in, const int* in_sizes, int n_in,
                              void* d_out, int out_size, void* d_ws, size_t ws_size,
                              hipStream_t stream) {
    const vf4* x = reinterpret_cast<const vf4*>(d_in[0]);
    vf4* out = reinterpret_cast<vf4*>(d_out);

    // total threads = N * G * F/4 = 256 * 128 * 32 = 1,048,576
    const int threads = 256;
    const int blocks = (256 * 128 * 32) / threads;  // 4096
    pool_space_kernel<<<blocks, threads, 0, stream>>>(x, out);
}

// Round 3
// 415.641 us; speedup vs baseline: 1.0653x; 1.0138x over previous
//
#include <hip/hip_runtime.h>

// x:   [N=256, 3, 3, num=256, F=128] fp32, C-order
// out: [N=256, 3, 3, G=128,  F=128] fp32
// Per (n,g,f): keep matrix 2g or 2g+1 with larger acos(clip((tr-1)/2,-1,1)).
// acos strictly decreasing => pick candidate 1 iff clip(c1) < clip(c0);
// ties -> candidate 0 (argmax first-max semantics).
//
// FINAL (R0 config restored after A/B/C probes):
//   NT loads + NT stores = 415.9 us  <- best
//   NT loads + plain stores = 421.4 us (R2: store-allocation neutral/negative)
//   plain loads + NT stores = 442.8 us (R1: re-poison fill flushes L3, so
//       allocating the 302 MB single-use read stream only thrashes)
// Timed window = 2 harness re-poison fills (~368 us at 82% HBM peak, fixed)
// + kernel slice ~48 us, which is BELOW the 453 MB / 6.3 TB/s = 72 us naive
// roofline (L3 absorbs part of the writes). Traffic is irreducible: the pick
// is data-dependent per element and candidates sit on disjoint cachelines.

typedef float vf4 __attribute__((ext_vector_type(4)));  // native clang vector:
// required because __builtin_nontemporal_load/store rejects HIP_vector_type.

__global__ __launch_bounds__(256) void pool_space_kernel(
    const vf4* __restrict__ x, vf4* __restrict__ out)
{
    constexpr int FV    = 32;              // F/4
    constexpr int G     = 128;
    constexpr int IN_E  = 256 * FV;        // 8192 vf4 per (i,j) plane
    constexpr int IN_N  = 9 * IN_E;
    constexpr int OUT_E = G * FV;          // 4096
    constexpr int OUT_N = 9 * OUT_E;

    const int tid = blockIdx.x * blockDim.x + threadIdx.x;
    const int fv  = tid & (FV - 1);
    const int g   = (tid >> 5) & (G - 1);
    const int n   = tid >> 12;

    const int inBase  = n * IN_N + (2 * g) * FV + fv;
    const int outBase = n * OUT_N + g * FV + fv;

    // Issue all 18 loads up front (max MLP). Diagonals first (they gate the pick).
    vf4 d0a = __builtin_nontemporal_load(&x[inBase + 0 * IN_E]);
    vf4 d0b = __builtin_nontemporal_load(&x[inBase + 0 * IN_E + FV]);
    vf4 d4a = __builtin_nontemporal_load(&x[inBase + 4 * IN_E]);
    vf4 d4b = __builtin_nontemporal_load(&x[inBase + 4 * IN_E + FV]);
    vf4 d8a = __builtin_nontemporal_load(&x[inBase + 8 * IN_E]);
    vf4 d8b = __builtin_nontemporal_load(&x[inBase + 8 * IN_E + FV]);

    vf4 oa[6], ob[6];
    constexpr int OD[6] = {1, 2, 3, 5, 6, 7};
#pragma unroll
    for (int i = 0; i < 6; ++i) {
        oa[i] = __builtin_nontemporal_load(&x[inBase + OD[i] * IN_E]);
        ob[i] = __builtin_nontemporal_load(&x[inBase + OD[i] * IN_E + FV]);
    }

    // Per-component pick: pk[k] true -> take candidate 1.
    bool pk[4];
#pragma unroll
    for (int k = 0; k < 4; ++k) {
        const float tr0 = d0a[k] + d4a[k] + d8a[k];
        const float tr1 = d0b[k] + d4b[k] + d8b[k];
        const float c0 = fminf(fmaxf((tr0 - 1.0f) * 0.5f, -1.0f), 1.0f);
        const float c1 = fminf(fmaxf((tr1 - 1.0f) * 0.5f, -1.0f), 1.0f);
        pk[k] = (c1 < c0);
    }

    auto sel = [&](vf4 a, vf4 b) {
        vf4 r;
        r[0] = pk[0] ? b[0] : a[0];
        r[1] = pk[1] ? b[1] : a[1];
        r[2] = pk[2] ? b[2] : a[2];
        r[3] = pk[3] ? b[3] : a[3];
        return r;
    };

    // Diagonal outputs reuse the already-loaded registers (no reload).
    __builtin_nontemporal_store(sel(d0a, d0b), &out[outBase + 0 * OUT_E]);
    __builtin_nontemporal_store(sel(d4a, d4b), &out[outBase + 4 * OUT_E]);
    __builtin_nontemporal_store(sel(d8a, d8b), &out[outBase + 8 * OUT_E]);
#pragma unroll
    for (int i = 0; i < 6; ++i) {
        __builtin_nontemporal_store(sel(oa[i], ob[i]), &out[outBase + OD[i] * OUT_E]);
    }
}

extern "C" void kernel_launch(void* const* d_in, const int* in_sizes, int n_in,
                              void* d_out, int out_size, void* d_ws, size_t ws_size,
                              hipStream_t stream) {
    const vf4* x = reinterpret_cast<const vf4*>(d_in[0]);
    vf4* out = reinterpret_cast<vf4*>(d_out);

    // total threads = N * G * F/4 = 256 * 128 * 32 = 1,048,576
    const int threads = 256;
    const int blocks = (256 * 128 * 32) / threads;  // 4096
    pool_space_kernel<<<blocks, threads, 0, stream>>>(x, out);
}